// Round 11
// baseline (308.755 us; speedup 1.0000x reference)
//
#include <hip/hip_runtime.h>
#include <hip/hip_bf16.h>

// Problem sizes (fixed by the reference)
#define NNODES 50000   // 3125 * 16 -> exact 16-row MFMA tiles
#define NEDGES 800000
#define NF 256         // input features
#define NH 128         // hidden
#define BN_EPS 1e-5f
#define MTILES (NNODES / 16)                 // 3125
#define CONV_BLOCKS 391                      // ceil(3125/8) strips, 8 waves/block
#define NBUCKETS 196                         // ceil(NNODES / 256)
#define BCAP 4608                            // bucket capacity: mean 4096 + 8 sigma
#define GEMM_BLOCKS 392                      // gemm_in: (pair, colhalf); 2 strips/wave
#define GEMM_WAVES 1568                      // strip pairs: strip0 0..1567, strip1 +1568
#define SCAT_BLOCKS 391                      // 2048 edges per block (512 thr x 4)
#define WC2_BLOCKS 128                       // conv-weight conversion: 65536 / 512
#define FRONT_BLOCKS (GEMM_BLOCKS + SCAT_BLOCKS + WC2_BLOCKS)  // 911

typedef __attribute__((ext_vector_type(8))) __bf16 bf16x8;  // MFMA A/B frag (4 VGPRs)
typedef __attribute__((ext_vector_type(4))) float floatx4;  // MFMA C/D frag

__device__ __forceinline__ __hip_bfloat16 f2bf(float f) { return __float2bfloat16(f); }
__device__ __forceinline__ float bits2f(unsigned short b) {
    union { unsigned u; float f; } u; u.u = ((unsigned)b) << 16; return u.f;
}

// load 8 consecutive fp32, round to bf16x8 MFMA fragment
__device__ __forceinline__ bf16x8 cvt8(const float* __restrict__ p) {
    floatx4 a0 = *(const floatx4*)p;
    floatx4 a1 = *(const floatx4*)(p + 4);
    bf16x8 r;
    r[0] = (__bf16)a0[0]; r[1] = (__bf16)a0[1]; r[2] = (__bf16)a0[2]; r[3] = (__bf16)a0[3];
    r[4] = (__bf16)a1[0]; r[5] = (__bf16)a1[1]; r[6] = (__bf16)a1[2]; r[7] = (__bf16)a1[3];
    return r;
}

// ---------------------------------------------------------------------------
// front: three independent block ranges in ONE 512-thread dispatch.
// R9/R10 showed front is throughput-bound on (total block-work)/(block slots)
// and slots were pinned at 2/CU by the 64KB LDS all branches paid for.
// This version HALVES LDS to 32KB by splitting gemm by output-col half:
// each gemm block stages 64 weight rows (32KB, frag order) and computes
// 2 strips x 64 cols. smem 32KB -> 4 blocks/CU (32-wave cap) -> 1024 slots.
// Cost: X read twice (+51MB via L3). launch_bounds(512,8) to allow 4 blk/CU.
//   [0, 392)      gemm_in: pair = bid>>1 (strips pair*8+wv and +1568),
//                 colhalf = bid&1 (output cols colhalf*64 .. +63)
//   [392, 783)    edge bucketing (CSR level 1), 4 edges/thread
//   [783, 911)    conv-weight fp32->bf16 conversion (W1r/W1o/W2r/W2o)
// ---------------------------------------------------------------------------
__global__ __launch_bounds__(512, 8) void front_kernel(
    const int* __restrict__ adj, const float* __restrict__ ew,
    int* __restrict__ gcursor, uint2* __restrict__ pairbuf,
    unsigned char* __restrict__ nodebuf,
    const float* __restrict__ W1r, const float* __restrict__ W1o,
    const float* __restrict__ W2r, const float* __restrict__ W2o,
    __hip_bfloat16* __restrict__ wbf,
    const float* __restrict__ X, const float* __restrict__ W_in,
    const float* __restrict__ b_in, __hip_bfloat16* __restrict__ h0)
{
    __shared__ char smem[32768];              // gemm: 128 frags | scatter: cnt/base
    const int tid = threadIdx.x;
    const int bid = blockIdx.x;

    if (bid < GEMM_BLOCKS) {                  // ---- gemm_in part ----
        const int ch = bid & 1;               // output col half: cols ch*64..+63
        {   // stage 64 weight rows fp32 -> bf16 frag order: F = (t4*8+kk)*4+qq
            const int rr = tid >> 3, part = tid & 7;   // 64 rows x 8 col-chunks
            const int t4 = rr >> 4, ar8 = rr & 15;
            const float* wsrc = W_in + (size_t)(ch * 64 + rr) * NF + part * 32;
            #pragma unroll
            for (int j = 0; j < 4; ++j) {
                const int col0 = part * 32 + j * 8;
                const int kk = col0 >> 5, qq = (col0 >> 3) & 3;
                const int F = (t4 * 8 + kk) * 4 + qq;
                *(bf16x8*)(smem + F * 256 + ar8 * 16) = cvt8(wsrc + j * 8);
            }
        }
        __syncthreads();

        const int wv = tid >> 6, lane = tid & 63;
        const int ar = lane & 15, q = lane >> 4;
        const int strip0 = (bid >> 1) * 8 + wv;     // 0..1567 (always active)
        const int strip1 = strip0 + GEMM_WAVES;     // 1568..3135, active < MTILES
        const bool hasB = (strip1 < MTILES);
        const int m0A = strip0 << 4;
        const int m0B = strip1 << 4;
        const char* wl = smem + q * 256 + ar * 16;

        floatx4 accA[4] = {}, accB[4] = {};
        #pragma unroll
        for (int kk = 0; kk < 8; ++kk) {
            const bf16x8 aA = cvt8(X + (size_t)(m0A + ar) * NF + kk * 32 + q * 8);
            bf16x8 aB;
            if (hasB) aB = cvt8(X + (size_t)(m0B + ar) * NF + kk * 32 + q * 8);
            #pragma unroll
            for (int t = 0; t < 4; ++t)
                accA[t] = __builtin_amdgcn_mfma_f32_16x16x32_bf16(
                    aA, *(const bf16x8*)(wl + ((t * 8 + kk) * 4) * 256), accA[t], 0, 0, 0);
            if (hasB) {
                #pragma unroll
                for (int t = 0; t < 4; ++t)
                    accB[t] = __builtin_amdgcn_mfma_f32_16x16x32_bf16(
                        aB, *(const bf16x8*)(wl + ((t * 8 + kk) * 4) * 256), accB[t], 0, 0, 0);
            }
        }
        #pragma unroll
        for (int t = 0; t < 4; ++t) {
            const int col = ch * 64 + t * 16 + ar;
            const float bvt = b_in[col];
            #pragma unroll
            for (int r2 = 0; r2 < 4; ++r2) {
                const float vA = fmaxf(accA[t][r2] + bvt, 0.f);
                h0[(size_t)(m0A + q * 4 + r2) * NH + col] = f2bf(vA);
            }
            if (hasB) {
                #pragma unroll
                for (int r2 = 0; r2 < 4; ++r2) {
                    const float vB = fmaxf(accB[t][r2] + bvt, 0.f);
                    h0[(size_t)(m0B + q * 4 + r2) * NH + col] = f2bf(vB);
                }
            }
        }
        return;
    }

    if (bid >= GEMM_BLOCKS + SCAT_BLOCKS) {   // ---- conv-weight conversion ----
        const int i = (bid - GEMM_BLOCKS - SCAT_BLOCKS) * 512 + tid;  // 0..65535
        const float* src; int off;
        if (i < 16384)      { src = W1r; off = i; }
        else if (i < 32768) { src = W1o; off = i - 16384; }
        else if (i < 49152) { src = W2r; off = i - 32768; }
        else                { src = W2o; off = i - 49152; }
        wbf[i] = f2bf(src[off]);
        return;
    }

    // ---- edge bucketing part ----
    int* cnt  = (int*)smem;
    int* base = (int*)(smem + 1024);
    if (tid < NBUCKETS) cnt[tid] = 0;
    __syncthreads();
    const int e0 = (bid - GEMM_BLOCKS) * 2048;
    #pragma unroll
    for (int i = 0; i < 4; ++i) {
        const int e = e0 + i * 512 + tid;
        if (e < NEDGES) atomicAdd(&cnt[adj[NEDGES + e] >> 8], 1);
    }
    __syncthreads();
    if (tid < NBUCKETS) {
        base[tid] = tid * BCAP + atomicAdd(&gcursor[tid], cnt[tid]);
        cnt[tid] = 0;
    }
    __syncthreads();
    #pragma unroll
    for (int i = 0; i < 4; ++i) {
        const int e = e0 + i * 512 + tid;
        if (e >= NEDGES) continue;
        const int dst = adj[NEDGES + e];
        const int b = dst >> 8;
        const int off = atomicAdd(&cnt[b], 1);
        const int slot = base[b] + off;
        if (slot < (b + 1) * BCAP) {          // overflow guard (P ~ 1e-10)
            pairbuf[slot] = make_uint2((unsigned)adj[e], __float_as_uint(ew[e]));
            nodebuf[slot] = (unsigned char)(dst & 255);
        }
    }
}

// ---------------------------------------------------------------------------
// CSR level 2: one block per bucket; counting sort by node within bucket.
// Row extent stored as int2 (beg, end) -> single 8B load in gather.
// ---------------------------------------------------------------------------
__global__ __launch_bounds__(256) void bucket_sort_kernel(
    const int* __restrict__ gcursor, const uint2* __restrict__ pairbuf,
    const unsigned char* __restrict__ nodebuf, uint2* __restrict__ sorted,
    int2* __restrict__ rowpair)
{
    const int b = blockIdx.x;
    const int tid = threadIdx.x;
    const int capbase = b * BCAP;
    int n = gcursor[b];                       // count (cursor is count)
    if (n > BCAP) n = BCAP;

    __shared__ int cnt[256];
    __shared__ int s[256];
    cnt[tid] = 0;
    __syncthreads();
    for (int j = tid; j < n; j += 256)
        atomicAdd(&cnt[nodebuf[capbase + j]], 1);
    __syncthreads();
    const int v = cnt[tid];
    s[tid] = v;
    __syncthreads();
    for (int off = 1; off < 256; off <<= 1) {
        const int t = (tid >= off) ? s[tid - off] : 0;
        __syncthreads();
        s[tid] += t;
        __syncthreads();
    }
    const int excl = s[tid] - v;
    const int node = b * 256 + tid;
    if (node < NNODES)
        rowpair[node] = make_int2(capbase + excl, capbase + excl + v);
    cnt[tid] = excl;                          // reuse as scatter cursor
    __syncthreads();
    for (int j = tid; j < n; j += 256) {
        const int nd = nodebuf[capbase + j];
        const int pos = atomicAdd(&cnt[nd], 1);
        sorted[capbase + pos] = pairbuf[capbase + j];
    }
}

// ---------------------------------------------------------------------------
// Gather-reduce: agg[n] = sum_{e in CSR[n]} w_e * h[src_e]   (bf16 out)
// One wave per node, 2 feats/lane, 8-way edge unroll (independent loads).
// ---------------------------------------------------------------------------
__global__ __launch_bounds__(256) void gather_kernel(
    const uint2* __restrict__ sorted, const int2* __restrict__ rowpair,
    const __hip_bfloat16* __restrict__ h, __hip_bfloat16* __restrict__ agg)
{
    const int node = blockIdx.x * 4 + (threadIdx.x >> 6);
    if (node >= NNODES) return;
    const int lane = threadIdx.x & 63;
    const int2 rp = rowpair[node];
    const int beg = rp.x;
    const int end = rp.y;
    const unsigned short* hb = (const unsigned short*)h;

    float a0[8] = {}, a1[8] = {};

    int j = beg;
    if ((j & 1) && j < end) {  // align to even index for uint4 loads
        const uint2 ev = sorted[j++];
        const float w = __uint_as_float(ev.y);
        const unsigned raw = *(const unsigned*)(hb + (size_t)ev.x * NH + lane * 2);
        a0[0] += w * bits2f((unsigned short)(raw & 0xffffu));
        a1[0] += w * bits2f((unsigned short)(raw >> 16));
    }
    for (; j + 8 <= end; j += 8) {
        const uint4 e01 = *(const uint4*)(sorted + j);
        const uint4 e23 = *(const uint4*)(sorted + j + 2);
        const uint4 e45 = *(const uint4*)(sorted + j + 4);
        const uint4 e67 = *(const uint4*)(sorted + j + 6);
        const unsigned r0 = *(const unsigned*)(hb + (size_t)e01.x * NH + lane * 2);
        const unsigned r1 = *(const unsigned*)(hb + (size_t)e01.z * NH + lane * 2);
        const unsigned r2 = *(const unsigned*)(hb + (size_t)e23.x * NH + lane * 2);
        const unsigned r3 = *(const unsigned*)(hb + (size_t)e23.z * NH + lane * 2);
        const unsigned r4 = *(const unsigned*)(hb + (size_t)e45.x * NH + lane * 2);
        const unsigned r5 = *(const unsigned*)(hb + (size_t)e45.z * NH + lane * 2);
        const unsigned r6 = *(const unsigned*)(hb + (size_t)e67.x * NH + lane * 2);
        const unsigned r7 = *(const unsigned*)(hb + (size_t)e67.z * NH + lane * 2);
        const float w0 = __uint_as_float(e01.y), w1 = __uint_as_float(e01.w);
        const float w2 = __uint_as_float(e23.y), w3 = __uint_as_float(e23.w);
        const float w4 = __uint_as_float(e45.y), w5 = __uint_as_float(e45.w);
        const float w6 = __uint_as_float(e67.y), w7 = __uint_as_float(e67.w);
        a0[0] += w0 * bits2f((unsigned short)(r0 & 0xffffu));
        a1[0] += w0 * bits2f((unsigned short)(r0 >> 16));
        a0[1] += w1 * bits2f((unsigned short)(r1 & 0xffffu));
        a1[1] += w1 * bits2f((unsigned short)(r1 >> 16));
        a0[2] += w2 * bits2f((unsigned short)(r2 & 0xffffu));
        a1[2] += w2 * bits2f((unsigned short)(r2 >> 16));
        a0[3] += w3 * bits2f((unsigned short)(r3 & 0xffffu));
        a1[3] += w3 * bits2f((unsigned short)(r3 >> 16));
        a0[4] += w4 * bits2f((unsigned short)(r4 & 0xffffu));
        a1[4] += w4 * bits2f((unsigned short)(r4 >> 16));
        a0[5] += w5 * bits2f((unsigned short)(r5 & 0xffffu));
        a1[5] += w5 * bits2f((unsigned short)(r5 >> 16));
        a0[6] += w6 * bits2f((unsigned short)(r6 & 0xffffu));
        a1[6] += w6 * bits2f((unsigned short)(r6 >> 16));
        a0[7] += w7 * bits2f((unsigned short)(r7 & 0xffffu));
        a1[7] += w7 * bits2f((unsigned short)(r7 >> 16));
    }
    for (; j + 2 <= end; j += 2) {
        const uint4 e01 = *(const uint4*)(sorted + j);
        const unsigned r0 = *(const unsigned*)(hb + (size_t)e01.x * NH + lane * 2);
        const unsigned r1 = *(const unsigned*)(hb + (size_t)e01.z * NH + lane * 2);
        const float w0 = __uint_as_float(e01.y), w1 = __uint_as_float(e01.w);
        a0[0] += w0 * bits2f((unsigned short)(r0 & 0xffffu));
        a1[0] += w0 * bits2f((unsigned short)(r0 >> 16));
        a0[1] += w1 * bits2f((unsigned short)(r1 & 0xffffu));
        a1[1] += w1 * bits2f((unsigned short)(r1 >> 16));
    }
    if (j < end) {
        const uint2 ev = sorted[j];
        const float w = __uint_as_float(ev.y);
        const unsigned raw = *(const unsigned*)(hb + (size_t)ev.x * NH + lane * 2);
        a0[0] += w * bits2f((unsigned short)(raw & 0xffffu));
        a1[0] += w * bits2f((unsigned short)(raw >> 16));
    }
    const float f0 = ((a0[0] + a0[1]) + (a0[2] + a0[3])) + ((a0[4] + a0[5]) + (a0[6] + a0[7]));
    const float f1 = ((a1[0] + a1[1]) + (a1[2] + a1[3])) + ((a1[4] + a1[5]) + (a1[6] + a1[7]));
    unsigned o = ((unsigned)__bfloat16_as_ushort(f2bf(f1)) << 16) |
                 (unsigned)__bfloat16_as_ushort(f2bf(f0));
    *(unsigned*)((unsigned short*)agg + (size_t)node * NH + lane * 2) = o;
}

// ---------------------------------------------------------------------------
// t = agg @ Wrel^T + h @ Wroot^T + b  (bf16 in, fp32 out) + fused BN stats.
// UNFUSED BN (grid-barrier fusion measured 76-101us in 4 variants: dead).
// acc lives only between the MFMA loop and the direct global store.
// Fragment-order LDS weights: conflict-free ds_read_b128. 64KB -> 2 blk/CU.
// ---------------------------------------------------------------------------
__global__ __launch_bounds__(512, 4) void gemm_conv_kernel(
    const __hip_bfloat16* __restrict__ agg, const __hip_bfloat16* __restrict__ h,
    const __hip_bfloat16* __restrict__ Wrel, const __hip_bfloat16* __restrict__ Wroot,
    const float* __restrict__ bias, float* __restrict__ out,
    float* __restrict__ stats)
{
    __shared__ char wlds[65536];              // 256 fragments x 256B, fragment order
    __shared__ float sst[256];
    const int tid = threadIdx.x;
    if (tid < 256) sst[tid] = 0.f;

    {   // stage weights -> fragment-order layout
        const int r = tid >> 2, part = tid & 3;
        const int mat = part >> 1;            // 0 = rel, 1 = root
        const int t8 = r >> 4, ar8 = r & 15;
        const __hip_bfloat16* wsrc =
            (mat ? Wroot : Wrel) + (size_t)r * NH + (part & 1) * 64;
        #pragma unroll
        for (int j = 0; j < 8; ++j) {
            const int col0 = (part & 1) * 64 + j * 8;
            const int kk = col0 >> 5, qq = (col0 >> 3) & 3;
            const int F = ((mat * 8 + t8) * 4 + kk) * 4 + qq;
            *(bf16x8*)(wlds + F * 256 + ar8 * 16) = *(const bf16x8*)(wsrc + j * 8);
        }
    }
    __syncthreads();                          // acc not yet live here

    const int wv = tid >> 6, lane = tid & 63;
    const int ar = lane & 15, q = lane >> 4;
    const int strip = blockIdx.x * 8 + wv;    // 0..3127, active < MTILES

    if (strip < MTILES) {
        const int m0 = strip << 4;
        const char* wl = wlds + q * 256 + ar * 16;

        floatx4 acc[8] = {};
        #pragma unroll
        for (int kk = 0; kk < 4; ++kk) {
            const bf16x8 a = *(const bf16x8*)(agg + (size_t)(m0 + ar) * NH + kk * 32 + q * 8);
            #pragma unroll
            for (int t = 0; t < 8; ++t)
                acc[t] = __builtin_amdgcn_mfma_f32_16x16x32_bf16(
                    a, *(const bf16x8*)(wl + ((t * 4 + kk) * 4) * 256), acc[t], 0, 0, 0);
        }
        #pragma unroll
        for (int kk = 0; kk < 4; ++kk) {
            const bf16x8 a = *(const bf16x8*)(h + (size_t)(m0 + ar) * NH + kk * 32 + q * 8);
            #pragma unroll
            for (int t = 0; t < 8; ++t)
                acc[t] = __builtin_amdgcn_mfma_f32_16x16x32_bf16(
                    a, *(const bf16x8*)(wl + (((8 + t) * 4 + kk) * 4) * 256), acc[t], 0, 0, 0);
        }

        // epilogue: bias, direct global store, column stats (acc dies HERE)
        #pragma unroll
        for (int t = 0; t < 8; ++t) {
            const float bvt = bias[t * 16 + ar];
            float s1 = 0.f, s2 = 0.f;
            #pragma unroll
            for (int r2 = 0; r2 < 4; ++r2) {
                const float v = acc[t][r2] + bvt;
                out[(size_t)(m0 + q * 4 + r2) * NH + t * 16 + ar] = v;
                s1 += v; s2 += v * v;
            }
            s1 += __shfl_xor(s1, 16, 64); s1 += __shfl_xor(s1, 32, 64);
            s2 += __shfl_xor(s2, 16, 64); s2 += __shfl_xor(s2, 32, 64);
            if (q == 0) {
                atomicAdd(&sst[t * 16 + ar], s1);
                atomicAdd(&sst[128 + t * 16 + ar], s2);
            }
        }
    }
    __syncthreads();
    if (tid < 256) unsafeAtomicAdd(&stats[tid], sst[tid]);
}

// ---------------------------------------------------------------------------
// BN normalize variants (x4 vectorized)
// ---------------------------------------------------------------------------
__global__ __launch_bounds__(256) void bn_relu_bf16_kernel(
    const float* __restrict__ t, const float* __restrict__ stats,
    const float* __restrict__ gamma, const float* __restrict__ beta,
    __hip_bfloat16* __restrict__ out)
{
    const size_t i = ((size_t)blockIdx.x * 256 + threadIdx.x) * 4;  // exact grid
    const float inv_n = 1.0f / (float)NNODES;
    const floatx4 v = *(const floatx4*)(t + i);
    ushort4 o;
    unsigned short* op = (unsigned short*)&o;
    #pragma unroll
    for (int j = 0; j < 4; ++j) {
        const int c = (int)((i + j) & (NH - 1));
        const float mu = stats[c] * inv_n;
        const float var = stats[128 + c] * inv_n - mu * mu;
        const float rs = rsqrtf(var + BN_EPS);
        const float y = (v[j] - mu) * rs * gamma[c] + beta[c];
        op[j] = __bfloat16_as_ushort(f2bf(fmaxf(y, 0.f)));
    }
    *(ushort4*)((unsigned short*)out + i) = o;
}

__global__ __launch_bounds__(256) void bn_f32_kernel(
    const float* __restrict__ t, const float* __restrict__ stats,
    const float* __restrict__ gamma, const float* __restrict__ beta,
    float* __restrict__ out)
{
    const size_t i = ((size_t)blockIdx.x * 256 + threadIdx.x) * 4;
    const float inv_n = 1.0f / (float)NNODES;
    const floatx4 v = *(const floatx4*)(t + i);
    floatx4 o;
    #pragma unroll
    for (int j = 0; j < 4; ++j) {
        const int c = (int)((i + j) & (NH - 1));
        const float mu = stats[c] * inv_n;
        const float var = stats[128 + c] * inv_n - mu * mu;
        const float rs = rsqrtf(var + BN_EPS);
        o[j] = (v[j] - mu) * rs * gamma[c] + beta[c];
    }
    *(floatx4*)(out + i) = o;
}

// ---------------------------------------------------------------------------

extern "C" void kernel_launch(void* const* d_in, const int* in_sizes, int n_in,
                              void* d_out, int out_size, void* d_ws, size_t ws_size,
                              hipStream_t stream)
{
    const float* x    = (const float*)d_in[0];
    const int*   adj  = (const int*)d_in[1];
    const float* ew   = (const float*)d_in[2];
    const float* W_in = (const float*)d_in[3];
    const float* b_in = (const float*)d_in[4];
    const float* W1r  = (const float*)d_in[5];
    const float* b1   = (const float*)d_in[6];
    const float* W1o  = (const float*)d_in[7];
    const float* W2r  = (const float*)d_in[8];
    const float* b2   = (const float*)d_in[9];
    const float* W2o  = (const float*)d_in[10];
    const float* gmm  = (const float*)d_in[11];
    const float* bta  = (const float*)d_in[12];
    float* out = (float*)d_out;          // fp32 output [N, NH]
    float* t   = (float*)d_out;          // pre-BN conv result lives in d_out

    char* ws = (char*)d_ws;
    __hip_bfloat16* h0  = (__hip_bfloat16*)ws; ws += (size_t)NNODES * NH * 2;  // 12.8 MB
    __hip_bfloat16* h1  = (__hip_bfloat16*)ws; ws += (size_t)NNODES * NH * 2;  // 12.8 MB
    __hip_bfloat16* agg = (__hip_bfloat16*)ws; ws += (size_t)NNODES * NH * 2;  // 12.8 MB
    uint2*          sorted  = (uint2*)ws;      ws += (size_t)NBUCKETS * BCAP * 8;  // 7.2 MB
    uint2*          pairbuf = (uint2*)ws;      ws += (size_t)NBUCKETS * BCAP * 8;  // 7.2 MB
    unsigned char*  nodebuf = (unsigned char*)ws; ws += (size_t)NBUCKETS * BCAP;   // 0.9 MB
    int2*           rowpair = (int2*)ws;       ws += NNODES * 8;
    // gcursor + st1 + st2 contiguous -> single 3 KB memset clears all
    int*            gcursor = (int*)ws;        ws += 256 * 4;
    float*          st1     = (float*)ws;      ws += 256 * 4;
    float*          st2     = (float*)ws;      ws += 256 * 4;
    __hip_bfloat16* wbf     = (__hip_bfloat16*)ws; ws += 65536 * 2;            // 128 KB

    const __hip_bfloat16* Wb1r = wbf;
    const __hip_bfloat16* Wb1o = wbf + 16384;
    const __hip_bfloat16* Wb2r = wbf + 32768;
    const __hip_bfloat16* Wb2o = wbf + 49152;

    const int node_blocks = (NNODES + 3) / 4;                   // 12500
    const int bn_blocks   = (NNODES * NH) / (256 * 4);          // 6250

    // ---- prep: zero cursors+stats, ONE front dispatch doing
    //      {gemm_in || edge bucketing || conv-weight convert}, then CSR sort
    hipMemsetAsync(gcursor, 0, 3 * 256 * 4, stream);
    front_kernel<<<FRONT_BLOCKS, 512, 0, stream>>>(
        adj, ew, gcursor, pairbuf, nodebuf, W1r, W1o, W2r, W2o, wbf,
        x, W_in, b_in, h0);
    bucket_sort_kernel<<<NBUCKETS, 256, 0, stream>>>(gcursor, pairbuf, nodebuf,
                                                     sorted, rowpair);

    // ---- layer 1 ----
    gather_kernel<<<node_blocks, 256, 0, stream>>>(sorted, rowpair, h0, agg);
    gemm_conv_kernel<<<CONV_BLOCKS, 512, 0, stream>>>(agg, h0, Wb1r, Wb1o, b1, t, st1);
    bn_relu_bf16_kernel<<<bn_blocks, 256, 0, stream>>>(t, st1, gmm, bta, h1);

    // ---- layer 2 ----
    gather_kernel<<<node_blocks, 256, 0, stream>>>(sorted, rowpair, h1, agg);
    gemm_conv_kernel<<<CONV_BLOCKS, 512, 0, stream>>>(agg, h1, Wb2r, Wb2o, b2, t, st2);
    bn_f32_kernel<<<bn_blocks, 256, 0, stream>>>(t, st2, gmm, bta, out);
}

// Round 12
// 289.388 us; speedup vs baseline: 1.0669x; 1.0669x over previous
//
#include <hip/hip_runtime.h>
#include <hip/hip_bf16.h>

// Problem sizes (fixed by the reference)
#define NNODES 50000   // 3125 * 16 -> exact 16-row MFMA tiles
#define NEDGES 800000
#define NF 256         // input features
#define NH 128         // hidden
#define BN_EPS 1e-5f
#define MTILES (NNODES / 16)                 // 3125
#define CONV_BLOCKS 391                      // ceil(3125/8) strips, 8 waves/block
#define NBUCKETS 196                         // ceil(NNODES / 256)
#define BCAP 4608                            // bucket capacity: mean 4096 + 8 sigma
#define GEMM_BLOCKS 392                      // gemm_in: (pair, colhalf); 2 strips/wave
#define GEMM_WAVES 1568                      // strip pairs: strip0 0..1567, strip1 +1568
#define SCAT_BLOCKS 391                      // 2048 edges per block (512 thr x 4)
#define WC2_BLOCKS 128                       // conv-weight conversion: 65536 / 512
#define FRONT_BLOCKS (GEMM_BLOCKS + SCAT_BLOCKS + WC2_BLOCKS)  // 911

typedef __attribute__((ext_vector_type(8))) __bf16 bf16x8;  // MFMA A/B frag (4 VGPRs)
typedef __attribute__((ext_vector_type(4))) float floatx4;  // MFMA C/D frag

__device__ __forceinline__ __hip_bfloat16 f2bf(float f) { return __float2bfloat16(f); }
__device__ __forceinline__ float bits2f(unsigned short b) {
    union { unsigned u; float f; } u; u.u = ((unsigned)b) << 16; return u.f;
}

// load 8 consecutive fp32, round to bf16x8 MFMA fragment
__device__ __forceinline__ bf16x8 cvt8(const float* __restrict__ p) {
    floatx4 a0 = *(const floatx4*)p;
    floatx4 a1 = *(const floatx4*)(p + 4);
    bf16x8 r;
    r[0] = (__bf16)a0[0]; r[1] = (__bf16)a0[1]; r[2] = (__bf16)a0[2]; r[3] = (__bf16)a0[3];
    r[4] = (__bf16)a1[0]; r[5] = (__bf16)a1[1]; r[6] = (__bf16)a1[2]; r[7] = (__bf16)a1[3];
    return r;
}

// ---------------------------------------------------------------------------
// front: three independent block ranges in ONE 512-thread dispatch.
// 32KB LDS via gemm col-split -> more block slots than R10's 64KB (2/CU).
// R11 ERRATUM: launch_bounds(512,8) capped VGPR at 32 -> acc spill (WRITE
// 58MB, front 64us). This round: (512,6) = 3 blocks/CU, VGPR budget ~85 >
// the ~60 the col-split needs -> no spill, slots 512 -> 768 (x1.5 vs R10).
//   [0, 392)      gemm_in: pair = bid>>1 (strips pair*8+wv and +1568),
//                 colhalf = bid&1 (output cols colhalf*64 .. +63)
//   [392, 783)    edge bucketing (CSR level 1), 4 edges/thread
//   [783, 911)    conv-weight fp32->bf16 conversion (W1r/W1o/W2r/W2o)
// ---------------------------------------------------------------------------
__global__ __launch_bounds__(512, 6) void front_kernel(
    const int* __restrict__ adj, const float* __restrict__ ew,
    int* __restrict__ gcursor, uint2* __restrict__ pairbuf,
    unsigned char* __restrict__ nodebuf,
    const float* __restrict__ W1r, const float* __restrict__ W1o,
    const float* __restrict__ W2r, const float* __restrict__ W2o,
    __hip_bfloat16* __restrict__ wbf,
    const float* __restrict__ X, const float* __restrict__ W_in,
    const float* __restrict__ b_in, __hip_bfloat16* __restrict__ h0)
{
    __shared__ char smem[32768];              // gemm: 128 frags | scatter: cnt/base
    const int tid = threadIdx.x;
    const int bid = blockIdx.x;

    if (bid < GEMM_BLOCKS) {                  // ---- gemm_in part ----
        const int ch = bid & 1;               // output col half: cols ch*64..+63
        {   // stage 64 weight rows fp32 -> bf16 frag order: F = (t4*8+kk)*4+qq
            const int rr = tid >> 3, part = tid & 7;   // 64 rows x 8 col-chunks
            const int t4 = rr >> 4, ar8 = rr & 15;
            const float* wsrc = W_in + (size_t)(ch * 64 + rr) * NF + part * 32;
            #pragma unroll
            for (int j = 0; j < 4; ++j) {
                const int col0 = part * 32 + j * 8;
                const int kk = col0 >> 5, qq = (col0 >> 3) & 3;
                const int F = (t4 * 8 + kk) * 4 + qq;
                *(bf16x8*)(smem + F * 256 + ar8 * 16) = cvt8(wsrc + j * 8);
            }
        }
        __syncthreads();

        const int wv = tid >> 6, lane = tid & 63;
        const int ar = lane & 15, q = lane >> 4;
        const int strip0 = (bid >> 1) * 8 + wv;     // 0..1567 (always active)
        const int strip1 = strip0 + GEMM_WAVES;     // 1568..3135, active < MTILES
        const bool hasB = (strip1 < MTILES);
        const int m0A = strip0 << 4;
        const int m0B = strip1 << 4;
        const char* wl = smem + q * 256 + ar * 16;

        floatx4 accA[4] = {}, accB[4] = {};
        #pragma unroll
        for (int kk = 0; kk < 8; ++kk) {
            const bf16x8 aA = cvt8(X + (size_t)(m0A + ar) * NF + kk * 32 + q * 8);
            bf16x8 aB;
            if (hasB) aB = cvt8(X + (size_t)(m0B + ar) * NF + kk * 32 + q * 8);
            #pragma unroll
            for (int t = 0; t < 4; ++t)
                accA[t] = __builtin_amdgcn_mfma_f32_16x16x32_bf16(
                    aA, *(const bf16x8*)(wl + ((t * 8 + kk) * 4) * 256), accA[t], 0, 0, 0);
            if (hasB) {
                #pragma unroll
                for (int t = 0; t < 4; ++t)
                    accB[t] = __builtin_amdgcn_mfma_f32_16x16x32_bf16(
                        aB, *(const bf16x8*)(wl + ((t * 8 + kk) * 4) * 256), accB[t], 0, 0, 0);
            }
        }
        #pragma unroll
        for (int t = 0; t < 4; ++t) {
            const int col = ch * 64 + t * 16 + ar;
            const float bvt = b_in[col];
            #pragma unroll
            for (int r2 = 0; r2 < 4; ++r2) {
                const float vA = fmaxf(accA[t][r2] + bvt, 0.f);
                h0[(size_t)(m0A + q * 4 + r2) * NH + col] = f2bf(vA);
            }
            if (hasB) {
                #pragma unroll
                for (int r2 = 0; r2 < 4; ++r2) {
                    const float vB = fmaxf(accB[t][r2] + bvt, 0.f);
                    h0[(size_t)(m0B + q * 4 + r2) * NH + col] = f2bf(vB);
                }
            }
        }
        return;
    }

    if (bid >= GEMM_BLOCKS + SCAT_BLOCKS) {   // ---- conv-weight conversion ----
        const int i = (bid - GEMM_BLOCKS - SCAT_BLOCKS) * 512 + tid;  // 0..65535
        const float* src; int off;
        if (i < 16384)      { src = W1r; off = i; }
        else if (i < 32768) { src = W1o; off = i - 16384; }
        else if (i < 49152) { src = W2r; off = i - 32768; }
        else                { src = W2o; off = i - 49152; }
        wbf[i] = f2bf(src[off]);
        return;
    }

    // ---- edge bucketing part ----
    int* cnt  = (int*)smem;
    int* base = (int*)(smem + 1024);
    if (tid < NBUCKETS) cnt[tid] = 0;
    __syncthreads();
    const int e0 = (bid - GEMM_BLOCKS) * 2048;
    #pragma unroll
    for (int i = 0; i < 4; ++i) {
        const int e = e0 + i * 512 + tid;
        if (e < NEDGES) atomicAdd(&cnt[adj[NEDGES + e] >> 8], 1);
    }
    __syncthreads();
    if (tid < NBUCKETS) {
        base[tid] = tid * BCAP + atomicAdd(&gcursor[tid], cnt[tid]);
        cnt[tid] = 0;
    }
    __syncthreads();
    #pragma unroll
    for (int i = 0; i < 4; ++i) {
        const int e = e0 + i * 512 + tid;
        if (e >= NEDGES) continue;
        const int dst = adj[NEDGES + e];
        const int b = dst >> 8;
        const int off = atomicAdd(&cnt[b], 1);
        const int slot = base[b] + off;
        if (slot < (b + 1) * BCAP) {          // overflow guard (P ~ 1e-10)
            pairbuf[slot] = make_uint2((unsigned)adj[e], __float_as_uint(ew[e]));
            nodebuf[slot] = (unsigned char)(dst & 255);
        }
    }
}

// ---------------------------------------------------------------------------
// CSR level 2: one block per bucket; counting sort by node within bucket.
// Row extent stored as int2 (beg, end) -> single 8B load in gather.
// ---------------------------------------------------------------------------
__global__ __launch_bounds__(256) void bucket_sort_kernel(
    const int* __restrict__ gcursor, const uint2* __restrict__ pairbuf,
    const unsigned char* __restrict__ nodebuf, uint2* __restrict__ sorted,
    int2* __restrict__ rowpair)
{
    const int b = blockIdx.x;
    const int tid = threadIdx.x;
    const int capbase = b * BCAP;
    int n = gcursor[b];                       // count (cursor is count)
    if (n > BCAP) n = BCAP;

    __shared__ int cnt[256];
    __shared__ int s[256];
    cnt[tid] = 0;
    __syncthreads();
    for (int j = tid; j < n; j += 256)
        atomicAdd(&cnt[nodebuf[capbase + j]], 1);
    __syncthreads();
    const int v = cnt[tid];
    s[tid] = v;
    __syncthreads();
    for (int off = 1; off < 256; off <<= 1) {
        const int t = (tid >= off) ? s[tid - off] : 0;
        __syncthreads();
        s[tid] += t;
        __syncthreads();
    }
    const int excl = s[tid] - v;
    const int node = b * 256 + tid;
    if (node < NNODES)
        rowpair[node] = make_int2(capbase + excl, capbase + excl + v);
    cnt[tid] = excl;                          // reuse as scatter cursor
    __syncthreads();
    for (int j = tid; j < n; j += 256) {
        const int nd = nodebuf[capbase + j];
        const int pos = atomicAdd(&cnt[nd], 1);
        sorted[capbase + pos] = pairbuf[capbase + j];
    }
}

// ---------------------------------------------------------------------------
// Gather-reduce: agg[n] = sum_{e in CSR[n]} w_e * h[src_e]   (bf16 out)
// One wave per node, 2 feats/lane, 8-way edge unroll (independent loads).
// ---------------------------------------------------------------------------
__global__ __launch_bounds__(256) void gather_kernel(
    const uint2* __restrict__ sorted, const int2* __restrict__ rowpair,
    const __hip_bfloat16* __restrict__ h, __hip_bfloat16* __restrict__ agg)
{
    const int node = blockIdx.x * 4 + (threadIdx.x >> 6);
    if (node >= NNODES) return;
    const int lane = threadIdx.x & 63;
    const int2 rp = rowpair[node];
    const int beg = rp.x;
    const int end = rp.y;
    const unsigned short* hb = (const unsigned short*)h;

    float a0[8] = {}, a1[8] = {};

    int j = beg;
    if ((j & 1) && j < end) {  // align to even index for uint4 loads
        const uint2 ev = sorted[j++];
        const float w = __uint_as_float(ev.y);
        const unsigned raw = *(const unsigned*)(hb + (size_t)ev.x * NH + lane * 2);
        a0[0] += w * bits2f((unsigned short)(raw & 0xffffu));
        a1[0] += w * bits2f((unsigned short)(raw >> 16));
    }
    for (; j + 8 <= end; j += 8) {
        const uint4 e01 = *(const uint4*)(sorted + j);
        const uint4 e23 = *(const uint4*)(sorted + j + 2);
        const uint4 e45 = *(const uint4*)(sorted + j + 4);
        const uint4 e67 = *(const uint4*)(sorted + j + 6);
        const unsigned r0 = *(const unsigned*)(hb + (size_t)e01.x * NH + lane * 2);
        const unsigned r1 = *(const unsigned*)(hb + (size_t)e01.z * NH + lane * 2);
        const unsigned r2 = *(const unsigned*)(hb + (size_t)e23.x * NH + lane * 2);
        const unsigned r3 = *(const unsigned*)(hb + (size_t)e23.z * NH + lane * 2);
        const unsigned r4 = *(const unsigned*)(hb + (size_t)e45.x * NH + lane * 2);
        const unsigned r5 = *(const unsigned*)(hb + (size_t)e45.z * NH + lane * 2);
        const unsigned r6 = *(const unsigned*)(hb + (size_t)e67.x * NH + lane * 2);
        const unsigned r7 = *(const unsigned*)(hb + (size_t)e67.z * NH + lane * 2);
        const float w0 = __uint_as_float(e01.y), w1 = __uint_as_float(e01.w);
        const float w2 = __uint_as_float(e23.y), w3 = __uint_as_float(e23.w);
        const float w4 = __uint_as_float(e45.y), w5 = __uint_as_float(e45.w);
        const float w6 = __uint_as_float(e67.y), w7 = __uint_as_float(e67.w);
        a0[0] += w0 * bits2f((unsigned short)(r0 & 0xffffu));
        a1[0] += w0 * bits2f((unsigned short)(r0 >> 16));
        a0[1] += w1 * bits2f((unsigned short)(r1 & 0xffffu));
        a1[1] += w1 * bits2f((unsigned short)(r1 >> 16));
        a0[2] += w2 * bits2f((unsigned short)(r2 & 0xffffu));
        a1[2] += w2 * bits2f((unsigned short)(r2 >> 16));
        a0[3] += w3 * bits2f((unsigned short)(r3 & 0xffffu));
        a1[3] += w3 * bits2f((unsigned short)(r3 >> 16));
        a0[4] += w4 * bits2f((unsigned short)(r4 & 0xffffu));
        a1[4] += w4 * bits2f((unsigned short)(r4 >> 16));
        a0[5] += w5 * bits2f((unsigned short)(r5 & 0xffffu));
        a1[5] += w5 * bits2f((unsigned short)(r5 >> 16));
        a0[6] += w6 * bits2f((unsigned short)(r6 & 0xffffu));
        a1[6] += w6 * bits2f((unsigned short)(r6 >> 16));
        a0[7] += w7 * bits2f((unsigned short)(r7 & 0xffffu));
        a1[7] += w7 * bits2f((unsigned short)(r7 >> 16));
    }
    for (; j + 2 <= end; j += 2) {
        const uint4 e01 = *(const uint4*)(sorted + j);
        const unsigned r0 = *(const unsigned*)(hb + (size_t)e01.x * NH + lane * 2);
        const unsigned r1 = *(const unsigned*)(hb + (size_t)e01.z * NH + lane * 2);
        const float w0 = __uint_as_float(e01.y), w1 = __uint_as_float(e01.w);
        a0[0] += w0 * bits2f((unsigned short)(r0 & 0xffffu));
        a1[0] += w0 * bits2f((unsigned short)(r0 >> 16));
        a0[1] += w1 * bits2f((unsigned short)(r1 & 0xffffu));
        a1[1] += w1 * bits2f((unsigned short)(r1 >> 16));
    }
    if (j < end) {
        const uint2 ev = sorted[j];
        const float w = __uint_as_float(ev.y);
        const unsigned raw = *(const unsigned*)(hb + (size_t)ev.x * NH + lane * 2);
        a0[0] += w * bits2f((unsigned short)(raw & 0xffffu));
        a1[0] += w * bits2f((unsigned short)(raw >> 16));
    }
    const float f0 = ((a0[0] + a0[1]) + (a0[2] + a0[3])) + ((a0[4] + a0[5]) + (a0[6] + a0[7]));
    const float f1 = ((a1[0] + a1[1]) + (a1[2] + a1[3])) + ((a1[4] + a1[5]) + (a1[6] + a1[7]));
    unsigned o = ((unsigned)__bfloat16_as_ushort(f2bf(f1)) << 16) |
                 (unsigned)__bfloat16_as_ushort(f2bf(f0));
    *(unsigned*)((unsigned short*)agg + (size_t)node * NH + lane * 2) = o;
}

// ---------------------------------------------------------------------------
// t = agg @ Wrel^T + h @ Wroot^T + b  (bf16 in, fp32 out) + fused BN stats.
// UNFUSED BN (grid-barrier fusion measured 76-101us in 4 variants: dead).
// acc lives only between the MFMA loop and the direct global store.
// Fragment-order LDS weights: conflict-free ds_read_b128. 64KB -> 2 blk/CU.
// ---------------------------------------------------------------------------
__global__ __launch_bounds__(512, 4) void gemm_conv_kernel(
    const __hip_bfloat16* __restrict__ agg, const __hip_bfloat16* __restrict__ h,
    const __hip_bfloat16* __restrict__ Wrel, const __hip_bfloat16* __restrict__ Wroot,
    const float* __restrict__ bias, float* __restrict__ out,
    float* __restrict__ stats)
{
    __shared__ char wlds[65536];              // 256 fragments x 256B, fragment order
    __shared__ float sst[256];
    const int tid = threadIdx.x;
    if (tid < 256) sst[tid] = 0.f;

    {   // stage weights -> fragment-order layout
        const int r = tid >> 2, part = tid & 3;
        const int mat = part >> 1;            // 0 = rel, 1 = root
        const int t8 = r >> 4, ar8 = r & 15;
        const __hip_bfloat16* wsrc =
            (mat ? Wroot : Wrel) + (size_t)r * NH + (part & 1) * 64;
        #pragma unroll
        for (int j = 0; j < 8; ++j) {
            const int col0 = (part & 1) * 64 + j * 8;
            const int kk = col0 >> 5, qq = (col0 >> 3) & 3;
            const int F = ((mat * 8 + t8) * 4 + kk) * 4 + qq;
            *(bf16x8*)(wlds + F * 256 + ar8 * 16) = *(const bf16x8*)(wsrc + j * 8);
        }
    }
    __syncthreads();                          // acc not yet live here

    const int wv = tid >> 6, lane = tid & 63;
    const int ar = lane & 15, q = lane >> 4;
    const int strip = blockIdx.x * 8 + wv;    // 0..3127, active < MTILES

    if (strip < MTILES) {
        const int m0 = strip << 4;
        const char* wl = wlds + q * 256 + ar * 16;

        floatx4 acc[8] = {};
        #pragma unroll
        for (int kk = 0; kk < 4; ++kk) {
            const bf16x8 a = *(const bf16x8*)(agg + (size_t)(m0 + ar) * NH + kk * 32 + q * 8);
            #pragma unroll
            for (int t = 0; t < 8; ++t)
                acc[t] = __builtin_amdgcn_mfma_f32_16x16x32_bf16(
                    a, *(const bf16x8*)(wl + ((t * 4 + kk) * 4) * 256), acc[t], 0, 0, 0);
        }
        #pragma unroll
        for (int kk = 0; kk < 4; ++kk) {
            const bf16x8 a = *(const bf16x8*)(h + (size_t)(m0 + ar) * NH + kk * 32 + q * 8);
            #pragma unroll
            for (int t = 0; t < 8; ++t)
                acc[t] = __builtin_amdgcn_mfma_f32_16x16x32_bf16(
                    a, *(const bf16x8*)(wl + (((8 + t) * 4 + kk) * 4) * 256), acc[t], 0, 0, 0);
        }

        // epilogue: bias, direct global store, column stats (acc dies HERE)
        #pragma unroll
        for (int t = 0; t < 8; ++t) {
            const float bvt = bias[t * 16 + ar];
            float s1 = 0.f, s2 = 0.f;
            #pragma unroll
            for (int r2 = 0; r2 < 4; ++r2) {
                const float v = acc[t][r2] + bvt;
                out[(size_t)(m0 + q * 4 + r2) * NH + t * 16 + ar] = v;
                s1 += v; s2 += v * v;
            }
            s1 += __shfl_xor(s1, 16, 64); s1 += __shfl_xor(s1, 32, 64);
            s2 += __shfl_xor(s2, 16, 64); s2 += __shfl_xor(s2, 32, 64);
            if (q == 0) {
                atomicAdd(&sst[t * 16 + ar], s1);
                atomicAdd(&sst[128 + t * 16 + ar], s2);
            }
        }
    }
    __syncthreads();
    if (tid < 256) unsafeAtomicAdd(&stats[tid], sst[tid]);
}

// ---------------------------------------------------------------------------
// BN normalize variants (x4 vectorized)
// ---------------------------------------------------------------------------
__global__ __launch_bounds__(256) void bn_relu_bf16_kernel(
    const float* __restrict__ t, const float* __restrict__ stats,
    const float* __restrict__ gamma, const float* __restrict__ beta,
    __hip_bfloat16* __restrict__ out)
{
    const size_t i = ((size_t)blockIdx.x * 256 + threadIdx.x) * 4;  // exact grid
    const float inv_n = 1.0f / (float)NNODES;
    const floatx4 v = *(const floatx4*)(t + i);
    ushort4 o;
    unsigned short* op = (unsigned short*)&o;
    #pragma unroll
    for (int j = 0; j < 4; ++j) {
        const int c = (int)((i + j) & (NH - 1));
        const float mu = stats[c] * inv_n;
        const float var = stats[128 + c] * inv_n - mu * mu;
        const float rs = rsqrtf(var + BN_EPS);
        const float y = (v[j] - mu) * rs * gamma[c] + beta[c];
        op[j] = __bfloat16_as_ushort(f2bf(fmaxf(y, 0.f)));
    }
    *(ushort4*)((unsigned short*)out + i) = o;
}

__global__ __launch_bounds__(256) void bn_f32_kernel(
    const float* __restrict__ t, const float* __restrict__ stats,
    const float* __restrict__ gamma, const float* __restrict__ beta,
    float* __restrict__ out)
{
    const size_t i = ((size_t)blockIdx.x * 256 + threadIdx.x) * 4;
    const float inv_n = 1.0f / (float)NNODES;
    const floatx4 v = *(const floatx4*)(t + i);
    floatx4 o;
    #pragma unroll
    for (int j = 0; j < 4; ++j) {
        const int c = (int)((i + j) & (NH - 1));
        const float mu = stats[c] * inv_n;
        const float var = stats[128 + c] * inv_n - mu * mu;
        const float rs = rsqrtf(var + BN_EPS);
        o[j] = (v[j] - mu) * rs * gamma[c] + beta[c];
    }
    *(floatx4*)(out + i) = o;
}

// ---------------------------------------------------------------------------

extern "C" void kernel_launch(void* const* d_in, const int* in_sizes, int n_in,
                              void* d_out, int out_size, void* d_ws, size_t ws_size,
                              hipStream_t stream)
{
    const float* x    = (const float*)d_in[0];
    const int*   adj  = (const int*)d_in[1];
    const float* ew   = (const float*)d_in[2];
    const float* W_in = (const float*)d_in[3];
    const float* b_in = (const float*)d_in[4];
    const float* W1r  = (const float*)d_in[5];
    const float* b1   = (const float*)d_in[6];
    const float* W1o  = (const float*)d_in[7];
    const float* W2r  = (const float*)d_in[8];
    const float* b2   = (const float*)d_in[9];
    const float* W2o  = (const float*)d_in[10];
    const float* gmm  = (const float*)d_in[11];
    const float* bta  = (const float*)d_in[12];
    float* out = (float*)d_out;          // fp32 output [N, NH]
    float* t   = (float*)d_out;          // pre-BN conv result lives in d_out

    char* ws = (char*)d_ws;
    __hip_bfloat16* h0  = (__hip_bfloat16*)ws; ws += (size_t)NNODES * NH * 2;  // 12.8 MB
    __hip_bfloat16* h1  = (__hip_bfloat16*)ws; ws += (size_t)NNODES * NH * 2;  // 12.8 MB
    __hip_bfloat16* agg = (__hip_bfloat16*)ws; ws += (size_t)NNODES * NH * 2;  // 12.8 MB
    uint2*          sorted  = (uint2*)ws;      ws += (size_t)NBUCKETS * BCAP * 8;  // 7.2 MB
    uint2*          pairbuf = (uint2*)ws;      ws += (size_t)NBUCKETS * BCAP * 8;  // 7.2 MB
    unsigned char*  nodebuf = (unsigned char*)ws; ws += (size_t)NBUCKETS * BCAP;   // 0.9 MB
    int2*           rowpair = (int2*)ws;       ws += NNODES * 8;
    // gcursor + st1 + st2 contiguous -> single 3 KB memset clears all
    int*            gcursor = (int*)ws;        ws += 256 * 4;
    float*          st1     = (float*)ws;      ws += 256 * 4;
    float*          st2     = (float*)ws;      ws += 256 * 4;
    __hip_bfloat16* wbf     = (__hip_bfloat16*)ws; ws += 65536 * 2;            // 128 KB

    const __hip_bfloat16* Wb1r = wbf;
    const __hip_bfloat16* Wb1o = wbf + 16384;
    const __hip_bfloat16* Wb2r = wbf + 32768;
    const __hip_bfloat16* Wb2o = wbf + 49152;

    const int node_blocks = (NNODES + 3) / 4;                   // 12500
    const int bn_blocks   = (NNODES * NH) / (256 * 4);          // 6250

    // ---- prep: zero cursors+stats, ONE front dispatch doing
    //      {gemm_in || edge bucketing || conv-weight convert}, then CSR sort
    hipMemsetAsync(gcursor, 0, 3 * 256 * 4, stream);
    front_kernel<<<FRONT_BLOCKS, 512, 0, stream>>>(
        adj, ew, gcursor, pairbuf, nodebuf, W1r, W1o, W2r, W2o, wbf,
        x, W_in, b_in, h0);
    bucket_sort_kernel<<<NBUCKETS, 256, 0, stream>>>(gcursor, pairbuf, nodebuf,
                                                     sorted, rowpair);

    // ---- layer 1 ----
    gather_kernel<<<node_blocks, 256, 0, stream>>>(sorted, rowpair, h0, agg);
    gemm_conv_kernel<<<CONV_BLOCKS, 512, 0, stream>>>(agg, h0, Wb1r, Wb1o, b1, t, st1);
    bn_relu_bf16_kernel<<<bn_blocks, 256, 0, stream>>>(t, st1, gmm, bta, h1);

    // ---- layer 2 ----
    gather_kernel<<<node_blocks, 256, 0, stream>>>(sorted, rowpair, h1, agg);
    gemm_conv_kernel<<<CONV_BLOCKS, 512, 0, stream>>>(agg, h1, Wb2r, Wb2o, b2, t, st2);
    bn_f32_kernel<<<bn_blocks, 256, 0, stream>>>(t, st2, gmm, bta, out);
}

// Round 13
// 279.873 us; speedup vs baseline: 1.1032x; 1.0340x over previous
//
#include <hip/hip_runtime.h>
#include <hip/hip_bf16.h>

// Problem sizes (fixed by the reference)
#define NNODES 50000   // 3125 * 16 -> exact 16-row MFMA tiles
#define NEDGES 800000
#define NF 256         // input features
#define NH 128         // hidden
#define BN_EPS 1e-5f
#define MTILES (NNODES / 16)                 // 3125
#define CONV_BLOCKS 391                      // ceil(3125/8) strips, 8 waves/block
#define NBUCKETS 196                         // ceil(NNODES / 256)
#define BCAP 4608                            // bucket capacity: mean 4096 + 8 sigma
#define GEMM_BLOCKS 196                      // gemm_in: 2 strips/wave, 1568 waves
#define GEMM_WAVES (GEMM_BLOCKS * 8)         // 1568
#define SCAT_BLOCKS 196                      // 4096 edges per block (512 thr x 8)
#define WC2_BLOCKS 32                        // conv-weight conversion: 65536/(512*4)
#define FRONT_BLOCKS (GEMM_BLOCKS + SCAT_BLOCKS + WC2_BLOCKS)  // 424 < 512 slots
                                             // -> SINGLE scheduling round @2blk/CU

typedef __attribute__((ext_vector_type(8))) __bf16 bf16x8;  // MFMA A/B frag (4 VGPRs)
typedef __attribute__((ext_vector_type(4))) float floatx4;  // MFMA C/D frag

__device__ __forceinline__ __hip_bfloat16 f2bf(float f) { return __float2bfloat16(f); }
__device__ __forceinline__ float bits2f(unsigned short b) {
    union { unsigned u; float f; } u; u.u = ((unsigned)b) << 16; return u.f;
}

// load 8 consecutive fp32, round to bf16x8 MFMA fragment
__device__ __forceinline__ bf16x8 cvt8(const float* __restrict__ p) {
    floatx4 a0 = *(const floatx4*)p;
    floatx4 a1 = *(const floatx4*)(p + 4);
    bf16x8 r;
    r[0] = (__bf16)a0[0]; r[1] = (__bf16)a0[1]; r[2] = (__bf16)a0[2]; r[3] = (__bf16)a0[3];
    r[4] = (__bf16)a1[0]; r[5] = (__bf16)a1[1]; r[6] = (__bf16)a1[2]; r[7] = (__bf16)a1[3];
    return r;
}

// ---------------------------------------------------------------------------
// front: three independent block ranges in ONE 512-thread dispatch.
// R10's gemm branch verified at VGPR=64, no spill (col-split abandoned:
// R11/R12 showed the allocator won't give 60 VGPRs at >4 waves/SIMD).
// NEW: block count compacted 715 -> 424 < 512 slots (2 blk/CU x 256 CU)
// so ALL front blocks run in a single scheduling round (no 203-block tail):
//   [0, 196)      gemm_in: 2 strips/wave interleaved, 64KB frag-order LDS
//   [196, 392)    edge bucketing, 4096 edges/block (8 x 512)
//   [392, 424)    conv-weight fp32->bf16, 4 elems/thread (float4->ushort4)
// ---------------------------------------------------------------------------
__global__ __launch_bounds__(512, 4) void front_kernel(
    const int* __restrict__ adj, const float* __restrict__ ew,
    int* __restrict__ gcursor, uint2* __restrict__ pairbuf,
    unsigned char* __restrict__ nodebuf,
    const float* __restrict__ W1r, const float* __restrict__ W1o,
    const float* __restrict__ W2r, const float* __restrict__ W2o,
    __hip_bfloat16* __restrict__ wbf,
    const float* __restrict__ X, const float* __restrict__ W_in,
    const float* __restrict__ b_in, __hip_bfloat16* __restrict__ h0)
{
    __shared__ char smem[65536];              // gemm: weight frags | scatter: cnt/base
    const int tid = threadIdx.x;
    const int bid = blockIdx.x;

    if (bid < GEMM_BLOCKS) {                  // ---- gemm_in part ----
        {   // stage W_in fp32 -> bf16 fragment order: F = (t8*8 + kk)*4 + qq
            const int r = tid >> 2, part = tid & 3;    // r: 128 rows, part: 64 cols
            const int t8 = r >> 4, ar8 = r & 15;
            const float* wsrc = W_in + (size_t)r * NF + part * 64;
            #pragma unroll
            for (int j = 0; j < 8; ++j) {
                const int col0 = part * 64 + j * 8;
                const int kk = col0 >> 5, qq = (col0 >> 3) & 3;
                const int F = (t8 * 8 + kk) * 4 + qq;
                *(bf16x8*)(smem + F * 256 + ar8 * 16) = cvt8(wsrc + j * 8);
            }
        }
        __syncthreads();

        const int wv = tid >> 6, lane = tid & 63;
        const int ar = lane & 15, q = lane >> 4;
        const int strip0 = bid * 8 + wv;      // 0..1567 (always active)
        const int strip1 = strip0 + GEMM_WAVES;  // 1568..3135, active < MTILES
        const bool hasB = (strip1 < MTILES);
        const int m0A = strip0 << 4;
        const int m0B = strip1 << 4;
        const char* wl = smem + q * 256 + ar * 16;

        floatx4 accA[8] = {}, accB[8] = {};
        #pragma unroll
        for (int kk = 0; kk < 8; ++kk) {
            const bf16x8 aA = cvt8(X + (size_t)(m0A + ar) * NF + kk * 32 + q * 8);
            bf16x8 aB;
            if (hasB) aB = cvt8(X + (size_t)(m0B + ar) * NF + kk * 32 + q * 8);
            #pragma unroll
            for (int t = 0; t < 8; ++t)
                accA[t] = __builtin_amdgcn_mfma_f32_16x16x32_bf16(
                    aA, *(const bf16x8*)(wl + ((t * 8 + kk) * 4) * 256), accA[t], 0, 0, 0);
            if (hasB) {
                #pragma unroll
                for (int t = 0; t < 8; ++t)
                    accB[t] = __builtin_amdgcn_mfma_f32_16x16x32_bf16(
                        aB, *(const bf16x8*)(wl + ((t * 8 + kk) * 4) * 256), accB[t], 0, 0, 0);
            }
        }
        #pragma unroll
        for (int t = 0; t < 8; ++t) {
            const float bvt = b_in[t * 16 + ar];
            #pragma unroll
            for (int r2 = 0; r2 < 4; ++r2) {
                const float vA = fmaxf(accA[t][r2] + bvt, 0.f);
                h0[(size_t)(m0A + q * 4 + r2) * NH + t * 16 + ar] = f2bf(vA);
            }
            if (hasB) {
                #pragma unroll
                for (int r2 = 0; r2 < 4; ++r2) {
                    const float vB = fmaxf(accB[t][r2] + bvt, 0.f);
                    h0[(size_t)(m0B + q * 4 + r2) * NH + t * 16 + ar] = f2bf(vB);
                }
            }
        }
        return;
    }

    if (bid >= GEMM_BLOCKS + SCAT_BLOCKS) {   // ---- conv-weight conversion ----
        const int i = (bid - GEMM_BLOCKS - SCAT_BLOCKS) * 2048 + tid * 4;  // 0..65532
        const float* src; int off;
        if (i < 16384)      { src = W1r; off = i; }
        else if (i < 32768) { src = W1o; off = i - 16384; }
        else if (i < 49152) { src = W2r; off = i - 32768; }
        else                { src = W2o; off = i - 49152; }
        const floatx4 v = *(const floatx4*)(src + off);
        ushort4 o;
        o.x = __bfloat16_as_ushort(f2bf(v[0]));
        o.y = __bfloat16_as_ushort(f2bf(v[1]));
        o.z = __bfloat16_as_ushort(f2bf(v[2]));
        o.w = __bfloat16_as_ushort(f2bf(v[3]));
        *(ushort4*)((unsigned short*)wbf + i) = o;
        return;
    }

    // ---- edge bucketing part: 4096 edges/block ----
    int* cnt  = (int*)smem;
    int* base = (int*)(smem + 1024);
    if (tid < NBUCKETS) cnt[tid] = 0;
    __syncthreads();
    const int e0 = (bid - GEMM_BLOCKS) * 4096;
    #pragma unroll
    for (int i = 0; i < 8; ++i) {
        const int e = e0 + i * 512 + tid;
        if (e < NEDGES) atomicAdd(&cnt[adj[NEDGES + e] >> 8], 1);
    }
    __syncthreads();
    if (tid < NBUCKETS) {
        base[tid] = tid * BCAP + atomicAdd(&gcursor[tid], cnt[tid]);
        cnt[tid] = 0;
    }
    __syncthreads();
    #pragma unroll
    for (int i = 0; i < 8; ++i) {
        const int e = e0 + i * 512 + tid;
        if (e >= NEDGES) continue;
        const int dst = adj[NEDGES + e];
        const int b = dst >> 8;
        const int off = atomicAdd(&cnt[b], 1);
        const int slot = base[b] + off;
        if (slot < (b + 1) * BCAP) {          // overflow guard (P ~ 1e-10)
            pairbuf[slot] = make_uint2((unsigned)adj[e], __float_as_uint(ew[e]));
            nodebuf[slot] = (unsigned char)(dst & 255);
        }
    }
}

// ---------------------------------------------------------------------------
// CSR level 2: one block per bucket; counting sort by node within bucket.
// Row extent stored as int2 (beg, end) -> single 8B load in gather.
// ---------------------------------------------------------------------------
__global__ __launch_bounds__(256) void bucket_sort_kernel(
    const int* __restrict__ gcursor, const uint2* __restrict__ pairbuf,
    const unsigned char* __restrict__ nodebuf, uint2* __restrict__ sorted,
    int2* __restrict__ rowpair)
{
    const int b = blockIdx.x;
    const int tid = threadIdx.x;
    const int capbase = b * BCAP;
    int n = gcursor[b];                       // count (cursor is count)
    if (n > BCAP) n = BCAP;

    __shared__ int cnt[256];
    __shared__ int s[256];
    cnt[tid] = 0;
    __syncthreads();
    for (int j = tid; j < n; j += 256)
        atomicAdd(&cnt[nodebuf[capbase + j]], 1);
    __syncthreads();
    const int v = cnt[tid];
    s[tid] = v;
    __syncthreads();
    for (int off = 1; off < 256; off <<= 1) {
        const int t = (tid >= off) ? s[tid - off] : 0;
        __syncthreads();
        s[tid] += t;
        __syncthreads();
    }
    const int excl = s[tid] - v;
    const int node = b * 256 + tid;
    if (node < NNODES)
        rowpair[node] = make_int2(capbase + excl, capbase + excl + v);
    cnt[tid] = excl;                          // reuse as scatter cursor
    __syncthreads();
    for (int j = tid; j < n; j += 256) {
        const int nd = nodebuf[capbase + j];
        const int pos = atomicAdd(&cnt[nd], 1);
        sorted[capbase + pos] = pairbuf[capbase + j];
    }
}

// ---------------------------------------------------------------------------
// Gather-reduce: agg[n] = sum_{e in CSR[n]} w_e * h[src_e]   (bf16 out)
// One wave per node, 2 feats/lane, 8-way edge unroll (independent loads).
// ---------------------------------------------------------------------------
__global__ __launch_bounds__(256) void gather_kernel(
    const uint2* __restrict__ sorted, const int2* __restrict__ rowpair,
    const __hip_bfloat16* __restrict__ h, __hip_bfloat16* __restrict__ agg)
{
    const int node = blockIdx.x * 4 + (threadIdx.x >> 6);
    if (node >= NNODES) return;
    const int lane = threadIdx.x & 63;
    const int2 rp = rowpair[node];
    const int beg = rp.x;
    const int end = rp.y;
    const unsigned short* hb = (const unsigned short*)h;

    float a0[8] = {}, a1[8] = {};

    int j = beg;
    if ((j & 1) && j < end) {  // align to even index for uint4 loads
        const uint2 ev = sorted[j++];
        const float w = __uint_as_float(ev.y);
        const unsigned raw = *(const unsigned*)(hb + (size_t)ev.x * NH + lane * 2);
        a0[0] += w * bits2f((unsigned short)(raw & 0xffffu));
        a1[0] += w * bits2f((unsigned short)(raw >> 16));
    }
    for (; j + 8 <= end; j += 8) {
        const uint4 e01 = *(const uint4*)(sorted + j);
        const uint4 e23 = *(const uint4*)(sorted + j + 2);
        const uint4 e45 = *(const uint4*)(sorted + j + 4);
        const uint4 e67 = *(const uint4*)(sorted + j + 6);
        const unsigned r0 = *(const unsigned*)(hb + (size_t)e01.x * NH + lane * 2);
        const unsigned r1 = *(const unsigned*)(hb + (size_t)e01.z * NH + lane * 2);
        const unsigned r2 = *(const unsigned*)(hb + (size_t)e23.x * NH + lane * 2);
        const unsigned r3 = *(const unsigned*)(hb + (size_t)e23.z * NH + lane * 2);
        const unsigned r4 = *(const unsigned*)(hb + (size_t)e45.x * NH + lane * 2);
        const unsigned r5 = *(const unsigned*)(hb + (size_t)e45.z * NH + lane * 2);
        const unsigned r6 = *(const unsigned*)(hb + (size_t)e67.x * NH + lane * 2);
        const unsigned r7 = *(const unsigned*)(hb + (size_t)e67.z * NH + lane * 2);
        const float w0 = __uint_as_float(e01.y), w1 = __uint_as_float(e01.w);
        const float w2 = __uint_as_float(e23.y), w3 = __uint_as_float(e23.w);
        const float w4 = __uint_as_float(e45.y), w5 = __uint_as_float(e45.w);
        const float w6 = __uint_as_float(e67.y), w7 = __uint_as_float(e67.w);
        a0[0] += w0 * bits2f((unsigned short)(r0 & 0xffffu));
        a1[0] += w0 * bits2f((unsigned short)(r0 >> 16));
        a0[1] += w1 * bits2f((unsigned short)(r1 & 0xffffu));
        a1[1] += w1 * bits2f((unsigned short)(r1 >> 16));
        a0[2] += w2 * bits2f((unsigned short)(r2 & 0xffffu));
        a1[2] += w2 * bits2f((unsigned short)(r2 >> 16));
        a0[3] += w3 * bits2f((unsigned short)(r3 & 0xffffu));
        a1[3] += w3 * bits2f((unsigned short)(r3 >> 16));
        a0[4] += w4 * bits2f((unsigned short)(r4 & 0xffffu));
        a1[4] += w4 * bits2f((unsigned short)(r4 >> 16));
        a0[5] += w5 * bits2f((unsigned short)(r5 & 0xffffu));
        a1[5] += w5 * bits2f((unsigned short)(r5 >> 16));
        a0[6] += w6 * bits2f((unsigned short)(r6 & 0xffffu));
        a1[6] += w6 * bits2f((unsigned short)(r6 >> 16));
        a0[7] += w7 * bits2f((unsigned short)(r7 & 0xffffu));
        a1[7] += w7 * bits2f((unsigned short)(r7 >> 16));
    }
    for (; j + 2 <= end; j += 2) {
        const uint4 e01 = *(const uint4*)(sorted + j);
        const unsigned r0 = *(const unsigned*)(hb + (size_t)e01.x * NH + lane * 2);
        const unsigned r1 = *(const unsigned*)(hb + (size_t)e01.z * NH + lane * 2);
        const float w0 = __uint_as_float(e01.y), w1 = __uint_as_float(e01.w);
        a0[0] += w0 * bits2f((unsigned short)(r0 & 0xffffu));
        a1[0] += w0 * bits2f((unsigned short)(r0 >> 16));
        a0[1] += w1 * bits2f((unsigned short)(r1 & 0xffffu));
        a1[1] += w1 * bits2f((unsigned short)(r1 >> 16));
    }
    if (j < end) {
        const uint2 ev = sorted[j];
        const float w = __uint_as_float(ev.y);
        const unsigned raw = *(const unsigned*)(hb + (size_t)ev.x * NH + lane * 2);
        a0[0] += w * bits2f((unsigned short)(raw & 0xffffu));
        a1[0] += w * bits2f((unsigned short)(raw >> 16));
    }
    const float f0 = ((a0[0] + a0[1]) + (a0[2] + a0[3])) + ((a0[4] + a0[5]) + (a0[6] + a0[7]));
    const float f1 = ((a1[0] + a1[1]) + (a1[2] + a1[3])) + ((a1[4] + a1[5]) + (a1[6] + a1[7]));
    unsigned o = ((unsigned)__bfloat16_as_ushort(f2bf(f1)) << 16) |
                 (unsigned)__bfloat16_as_ushort(f2bf(f0));
    *(unsigned*)((unsigned short*)agg + (size_t)node * NH + lane * 2) = o;
}

// ---------------------------------------------------------------------------
// t = agg @ Wrel^T + h @ Wroot^T + b  (bf16 in, fp32 out) + fused BN stats.
// UNFUSED BN (grid-barrier fusion measured 76-101us in 4 variants: dead).
// acc lives only between the MFMA loop and the direct global store.
// Fragment-order LDS weights: conflict-free ds_read_b128. 64KB -> 2 blk/CU.
// ---------------------------------------------------------------------------
__global__ __launch_bounds__(512, 4) void gemm_conv_kernel(
    const __hip_bfloat16* __restrict__ agg, const __hip_bfloat16* __restrict__ h,
    const __hip_bfloat16* __restrict__ Wrel, const __hip_bfloat16* __restrict__ Wroot,
    const float* __restrict__ bias, float* __restrict__ out,
    float* __restrict__ stats)
{
    __shared__ char wlds[65536];              // 256 fragments x 256B, fragment order
    __shared__ float sst[256];
    const int tid = threadIdx.x;
    if (tid < 256) sst[tid] = 0.f;

    {   // stage weights -> fragment-order layout
        const int r = tid >> 2, part = tid & 3;
        const int mat = part >> 1;            // 0 = rel, 1 = root
        const int t8 = r >> 4, ar8 = r & 15;
        const __hip_bfloat16* wsrc =
            (mat ? Wroot : Wrel) + (size_t)r * NH + (part & 1) * 64;
        #pragma unroll
        for (int j = 0; j < 8; ++j) {
            const int col0 = (part & 1) * 64 + j * 8;
            const int kk = col0 >> 5, qq = (col0 >> 3) & 3;
            const int F = ((mat * 8 + t8) * 4 + kk) * 4 + qq;
            *(bf16x8*)(wlds + F * 256 + ar8 * 16) = *(const bf16x8*)(wsrc + j * 8);
        }
    }
    __syncthreads();                          // acc not yet live here

    const int wv = tid >> 6, lane = tid & 63;
    const int ar = lane & 15, q = lane >> 4;
    const int strip = blockIdx.x * 8 + wv;    // 0..3127, active < MTILES

    if (strip < MTILES) {
        const int m0 = strip << 4;
        const char* wl = wlds + q * 256 + ar * 16;

        floatx4 acc[8] = {};
        #pragma unroll
        for (int kk = 0; kk < 4; ++kk) {
            const bf16x8 a = *(const bf16x8*)(agg + (size_t)(m0 + ar) * NH + kk * 32 + q * 8);
            #pragma unroll
            for (int t = 0; t < 8; ++t)
                acc[t] = __builtin_amdgcn_mfma_f32_16x16x32_bf16(
                    a, *(const bf16x8*)(wl + ((t * 4 + kk) * 4) * 256), acc[t], 0, 0, 0);
        }
        #pragma unroll
        for (int kk = 0; kk < 4; ++kk) {
            const bf16x8 a = *(const bf16x8*)(h + (size_t)(m0 + ar) * NH + kk * 32 + q * 8);
            #pragma unroll
            for (int t = 0; t < 8; ++t)
                acc[t] = __builtin_amdgcn_mfma_f32_16x16x32_bf16(
                    a, *(const bf16x8*)(wl + (((8 + t) * 4 + kk) * 4) * 256), acc[t], 0, 0, 0);
        }

        // epilogue: bias, direct global store, column stats (acc dies HERE)
        #pragma unroll
        for (int t = 0; t < 8; ++t) {
            const float bvt = bias[t * 16 + ar];
            float s1 = 0.f, s2 = 0.f;
            #pragma unroll
            for (int r2 = 0; r2 < 4; ++r2) {
                const float v = acc[t][r2] + bvt;
                out[(size_t)(m0 + q * 4 + r2) * NH + t * 16 + ar] = v;
                s1 += v; s2 += v * v;
            }
            s1 += __shfl_xor(s1, 16, 64); s1 += __shfl_xor(s1, 32, 64);
            s2 += __shfl_xor(s2, 16, 64); s2 += __shfl_xor(s2, 32, 64);
            if (q == 0) {
                atomicAdd(&sst[t * 16 + ar], s1);
                atomicAdd(&sst[128 + t * 16 + ar], s2);
            }
        }
    }
    __syncthreads();
    if (tid < 256) unsafeAtomicAdd(&stats[tid], sst[tid]);
}

// ---------------------------------------------------------------------------
// BN normalize variants (x4 vectorized)
// ---------------------------------------------------------------------------
__global__ __launch_bounds__(256) void bn_relu_bf16_kernel(
    const float* __restrict__ t, const float* __restrict__ stats,
    const float* __restrict__ gamma, const float* __restrict__ beta,
    __hip_bfloat16* __restrict__ out)
{
    const size_t i = ((size_t)blockIdx.x * 256 + threadIdx.x) * 4;  // exact grid
    const float inv_n = 1.0f / (float)NNODES;
    const floatx4 v = *(const floatx4*)(t + i);
    ushort4 o;
    unsigned short* op = (unsigned short*)&o;
    #pragma unroll
    for (int j = 0; j < 4; ++j) {
        const int c = (int)((i + j) & (NH - 1));
        const float mu = stats[c] * inv_n;
        const float var = stats[128 + c] * inv_n - mu * mu;
        const float rs = rsqrtf(var + BN_EPS);
        const float y = (v[j] - mu) * rs * gamma[c] + beta[c];
        op[j] = __bfloat16_as_ushort(f2bf(fmaxf(y, 0.f)));
    }
    *(ushort4*)((unsigned short*)out + i) = o;
}

__global__ __launch_bounds__(256) void bn_f32_kernel(
    const float* __restrict__ t, const float* __restrict__ stats,
    const float* __restrict__ gamma, const float* __restrict__ beta,
    float* __restrict__ out)
{
    const size_t i = ((size_t)blockIdx.x * 256 + threadIdx.x) * 4;
    const float inv_n = 1.0f / (float)NNODES;
    const floatx4 v = *(const floatx4*)(t + i);
    floatx4 o;
    #pragma unroll
    for (int j = 0; j < 4; ++j) {
        const int c = (int)((i + j) & (NH - 1));
        const float mu = stats[c] * inv_n;
        const float var = stats[128 + c] * inv_n - mu * mu;
        const float rs = rsqrtf(var + BN_EPS);
        o[j] = (v[j] - mu) * rs * gamma[c] + beta[c];
    }
    *(floatx4*)(out + i) = o;
}

// ---------------------------------------------------------------------------

extern "C" void kernel_launch(void* const* d_in, const int* in_sizes, int n_in,
                              void* d_out, int out_size, void* d_ws, size_t ws_size,
                              hipStream_t stream)
{
    const float* x    = (const float*)d_in[0];
    const int*   adj  = (const int*)d_in[1];
    const float* ew   = (const float*)d_in[2];
    const float* W_in = (const float*)d_in[3];
    const float* b_in = (const float*)d_in[4];
    const float* W1r  = (const float*)d_in[5];
    const float* b1   = (const float*)d_in[6];
    const float* W1o  = (const float*)d_in[7];
    const float* W2r  = (const float*)d_in[8];
    const float* b2   = (const float*)d_in[9];
    const float* W2o  = (const float*)d_in[10];
    const float* gmm  = (const float*)d_in[11];
    const float* bta  = (const float*)d_in[12];
    float* out = (float*)d_out;          // fp32 output [N, NH]
    float* t   = (float*)d_out;          // pre-BN conv result lives in d_out

    char* ws = (char*)d_ws;
    __hip_bfloat16* h0  = (__hip_bfloat16*)ws; ws += (size_t)NNODES * NH * 2;  // 12.8 MB
    __hip_bfloat16* h1  = (__hip_bfloat16*)ws; ws += (size_t)NNODES * NH * 2;  // 12.8 MB
    __hip_bfloat16* agg = (__hip_bfloat16*)ws; ws += (size_t)NNODES * NH * 2;  // 12.8 MB
    uint2*          sorted  = (uint2*)ws;      ws += (size_t)NBUCKETS * BCAP * 8;  // 7.2 MB
    uint2*          pairbuf = (uint2*)ws;      ws += (size_t)NBUCKETS * BCAP * 8;  // 7.2 MB
    unsigned char*  nodebuf = (unsigned char*)ws; ws += (size_t)NBUCKETS * BCAP;   // 0.9 MB
    int2*           rowpair = (int2*)ws;       ws += NNODES * 8;
    // gcursor + st1 + st2 contiguous -> single 3 KB memset clears all
    int*            gcursor = (int*)ws;        ws += 256 * 4;
    float*          st1     = (float*)ws;      ws += 256 * 4;
    float*          st2     = (float*)ws;      ws += 256 * 4;
    __hip_bfloat16* wbf     = (__hip_bfloat16*)ws; ws += 65536 * 2;            // 128 KB

    const __hip_bfloat16* Wb1r = wbf;
    const __hip_bfloat16* Wb1o = wbf + 16384;
    const __hip_bfloat16* Wb2r = wbf + 32768;
    const __hip_bfloat16* Wb2o = wbf + 49152;

    const int node_blocks = (NNODES + 3) / 4;                   // 12500
    const int bn_blocks   = (NNODES * NH) / (256 * 4);          // 6250

    // ---- prep: zero cursors+stats, ONE front dispatch doing
    //      {gemm_in || edge bucketing || conv-weight convert}, then CSR sort
    hipMemsetAsync(gcursor, 0, 3 * 256 * 4, stream);
    front_kernel<<<FRONT_BLOCKS, 512, 0, stream>>>(
        adj, ew, gcursor, pairbuf, nodebuf, W1r, W1o, W2r, W2o, wbf,
        x, W_in, b_in, h0);
    bucket_sort_kernel<<<NBUCKETS, 256, 0, stream>>>(gcursor, pairbuf, nodebuf,
                                                     sorted, rowpair);

    // ---- layer 1 ----
    gather_kernel<<<node_blocks, 256, 0, stream>>>(sorted, rowpair, h0, agg);
    gemm_conv_kernel<<<CONV_BLOCKS, 512, 0, stream>>>(agg, h0, Wb1r, Wb1o, b1, t, st1);
    bn_relu_bf16_kernel<<<bn_blocks, 256, 0, stream>>>(t, st1, gmm, bta, h1);

    // ---- layer 2 ----
    gather_kernel<<<node_blocks, 256, 0, stream>>>(sorted, rowpair, h1, agg);
    gemm_conv_kernel<<<CONV_BLOCKS, 512, 0, stream>>>(agg, h1, Wb2r, Wb2o, b2, t, st2);
    bn_f32_kernel<<<bn_blocks, 256, 0, stream>>>(t, st2, gmm, bta, out);
}